// Round 5
// baseline (665.148 us; speedup 1.0000x reference)
//
#include <hip/hip_runtime.h>

// Problem constants (from reference)
#define BB 8
#define CC 64
#define TT 50
#define HH 64
#define WW 64
#define HO 32
#define WO 32
#define PLANE (HH * WW)                 // 4096 floats per (b,c,t) plane
#define BC_STRIDE (TT * PLANE)          // 204800 floats per (b,c)
#define OUT_T_STRIDE (HO * WO)          // 1024
#define OUT_BC_STRIDE (TT * OUT_T_STRIDE)   // 51200
#define N_OUT_MAIN (BB * CC * OUT_BC_STRIDE) // 26214400 (loss scalar follows)

// clang ext_vector alias: __builtin_nontemporal_store rejects HIP's float2
// class; this POD vector has identical layout and is accepted.
typedef float f2_t __attribute__((ext_vector_type(2)));

// Single-pass-over-HBM, float4 edition:
//   Grid = B*C*(H/16) = 2048 blocks of 256 threads.
//   Each block owns input rows [16R, 16R+16) x all 64 cols x all 50 t.
//   Thread tid: rr = tid>>4 (row 0..15), wq = tid&15 (float4-col).
//   Each thread owns FOUR horizontal pixels (one float4 = top/bottom half of
//   TWO 2x2 windows) for the full time series: float4 pix[50] = 200 VGPRs.
//   Vertical window partner is lane tid^16 (same wave): argmax inputs and
//   per-t winner values move via __shfl_xor(.,16). No LDS, no re-read.
//
//   HBM traffic: read x exactly once (419 MB, 16 B/lane coalesced),
//   write out exactly once (105 MB, full-line nontemporal stores).
//   __launch_bounds__(256,2): VGPR cap 256 (~230 used, no spill),
//   8 waves/CU; 50 independent loads/thread gives ample MLP at that occupancy.
__global__ __launch_bounds__(256, 2)
void spike_pool_kernel(const float* __restrict__ x, float* __restrict__ out) {
    const int blk = blockIdx.x;      // 0..2047
    const int bc  = blk >> 2;        // 0..511  (b*64 + c)
    const int R   = blk & 3;         // row-group: input rows [16R, 16R+16)
    const int tid = threadIdx.x;     // 0..255

    // Block's per-t chunk is 16 rows * 64 cols = 4 KB, contiguous.
    // Thread's float4 sits at float4-index tid within that chunk.
    const float4* __restrict__ base =
        (const float4*)(x + (size_t)bc * BC_STRIDE + R * 16 * WW);

    // ---- Pass 1: stream x once; keep time series in regs; fold the
    // reference's sequential fp32 cumsum-then-sum per pixel (bit-identical
    // x_sum -> identical first-max argmax). ----
    float4 pix[TT];
    float cx = 0.f, cy = 0.f, cz = 0.f, cw = 0.f;
    float sx = 0.f, sy = 0.f, sz = 0.f, sw = 0.f;
#pragma unroll
    for (int t = 0; t < TT; ++t) {
        float4 v = base[(size_t)t * (PLANE / 4) + tid];
        pix[t] = v;
        cx += v.x; sx += cx;
        cy += v.y; sy += cy;
        cz += v.z; sz += cz;
        cw += v.w; sw += cw;
    }

    // ---- Window argmax (first-max, reference candidate order a,a+1,a+W,a+W+1).
    // Vertical partner (other row of both windows) is lane tid^16, same wave.
    const float ox_ = __shfl_xor(sx, 16);
    const float oy_ = __shfl_xor(sy, 16);
    const float oz_ = __shfl_xor(sz, 16);
    const float ow_ = __shfl_xor(sw, 16);
    const bool top = ((tid >> 4) & 1) == 0;   // rr even -> top row of windows

    // Window 0 = cols (4wq, 4wq+1); window 1 = cols (4wq+2, 4wq+3).
    const float w0a = top ? sx  : ox_;   // a       (top-left)
    const float w0b = top ? sy  : oy_;   // a+1     (top-right)
    const float w0c = top ? ox_ : sx;    // a+W     (bottom-left)
    const float w0d = top ? oy_ : sy;    // a+W+1   (bottom-right)
    int win0 = 0; float bv0 = w0a;
    if (w0b > bv0) { bv0 = w0b; win0 = 1; }
    if (w0c > bv0) { bv0 = w0c; win0 = 2; }
    if (w0d > bv0) { bv0 = w0d; win0 = 3; }

    const float w1a = top ? sz  : oz_;
    const float w1b = top ? sw  : ow_;
    const float w1c = top ? oz_ : sz;
    const float w1d = top ? ow_ : sw;
    int win1 = 0; float bv1 = w1a;
    if (w1b > bv1) { bv1 = w1b; win1 = 1; }
    if (w1c > bv1) { bv1 = w1c; win1 = 2; }
    if (w1d > bv1) { bv1 = w1d; win1 = 3; }
    // Both lanes of a pair compute identical win0/win1 (same 4 inputs).

    const int  col0 = win0 & 1, col1 = win1 & 1;        // winner column in pair
    const bool cross0 = top ? (win0 >= 2) : (win0 < 2); // winner on partner row?
    const bool cross1 = top ? (win1 >= 2) : (win1 < 2);

    // Output: window row = 8R + (rr>>1), window cols (2wq, 2wq+1) -> float2.
    float* __restrict__ obase = out + (size_t)bc * OUT_BC_STRIDE
                              + (size_t)(R * 8 + ((tid >> 4) >> 1)) * WO
                              + 2 * (tid & 15);

    // ---- Pass 2: winner gather straight from registers. Two timesteps per
    // iteration: top lanes store t, bottom lanes store t+1 (one full-wave
    // 8 B store = 4 x fully-covered 128 B segments per wave). ----
#pragma unroll
    for (int t = 0; t < TT; t += 2) {
        const float a0 = col0 ? pix[t].y     : pix[t].x;
        const float a1 = col1 ? pix[t].w     : pix[t].z;
        const float b0 = col0 ? pix[t + 1].y : pix[t + 1].x;
        const float b1 = col1 ? pix[t + 1].w : pix[t + 1].z;
        const float xa0 = __shfl_xor(a0, 16);   // all lanes shuffle pre-branch
        const float xa1 = __shfl_xor(a1, 16);
        const float xb0 = __shfl_xor(b0, 16);
        const float xb1 = __shfl_xor(b1, 16);
        f2_t o; size_t off;
        if (top) {
            o.x = cross0 ? xa0 : a0;
            o.y = cross1 ? xa1 : a1;
            off = (size_t)t * OUT_T_STRIDE;
        } else {
            o.x = cross0 ? xb0 : b0;
            o.y = cross1 ? xb1 : b1;
            off = (size_t)(t + 1) * OUT_T_STRIDE;
        }
        __builtin_nontemporal_store(o, (f2_t*)(obase + off));
    }

    // Scalar loss output (= 0.0f), appended after spk_rec.
    if (blk == 0 && tid == 0) out[N_OUT_MAIN] = 0.0f;
}

extern "C" void kernel_launch(void* const* d_in, const int* in_sizes, int n_in,
                              void* d_out, int out_size, void* d_ws, size_t ws_size,
                              hipStream_t stream) {
    const float* x = (const float*)d_in[0];
    float* out = (float*)d_out;
    dim3 grid(BB * CC * (HH / 16));   // 2048
    dim3 block(256);
    spike_pool_kernel<<<grid, block, 0, stream>>>(x, out);
}

// Round 7
// 647.020 us; speedup vs baseline: 1.0280x; 1.0280x over previous
//
#include <hip/hip_runtime.h>

// Problem constants (from reference)
#define BB 8
#define CC 64
#define TT 50
#define HH 64
#define WW 64
#define HO 32
#define WO 32
#define PLANE (HH * WW)                 // 4096 floats per (b,c,t) plane
#define BC_STRIDE (TT * PLANE)          // 204800 floats per (b,c)
#define OUT_T_STRIDE (HO * WO)          // 1024
#define OUT_BC_STRIDE (TT * OUT_T_STRIDE)   // 51200
#define N_OUT_MAIN (BB * CC * OUT_BC_STRIDE) // 26214400 (loss scalar follows)

// Single-pass-over-HBM design (round-1 float2 structure, measured 646.7 us
// total @ launch_bounds(256,3); this round's ONLY change: min-waves 3 -> 4).
//   Grid = B*C*(H/8) = 4096 blocks of 256 threads.
//   4 blocks/CU resident -> 4096/1024 = exactly 4 block-rounds (no tail;
//   at 3/CU it was 5.33 rounds, ~10% tail idle).
//   Each thread owns ONE horizontal pixel pair (row 8R+rr, cols 2wo..2wo+1)
//   for the full time series: float2 pix[50] = 100 VGPRs (+~25 overhead,
//   fits the 128-VGPR cap of 4 waves/SIMD; spill would show as regression).
//   A 2x2 window's two pixel pairs live in lanes tid and tid^32 (same wave):
//   argmax inputs and per-t winner values move via __shfl_xor(.,32).
//
//   HBM traffic: read x exactly once (419 MB, coalesced 8 B/lane),
//   write out exactly once (105 MB). No LDS. No scattered gathers.
__global__ __launch_bounds__(256, 4)
void spike_pool_kernel(const float* __restrict__ x, float* __restrict__ out) {
    const int blk = blockIdx.x;      // 0..4095
    const int bc  = blk >> 3;        // 0..511  (b*64 + c)
    const int R   = blk & 7;         // row-group: input rows [8R, 8R+8)
    const int tid = threadIdx.x;     // 0..255; rr = tid>>5 in [0,8), wo = tid&31

    // Block's per-t chunk is 8 rows * 64 cols = 2 KB, contiguous.
    // Thread's float2 sits at float2-index tid within that chunk.
    const float2* __restrict__ base =
        (const float2*)(x + (size_t)bc * BC_STRIDE + R * 8 * WW);

    // ---- Pass 1: stream x once; keep time series in regs; fold the
    // reference's sequential fp32 cumsum-then-sum per pixel (bit-identical
    // x_sum -> identical first-max argmax). ----
    float2 pix[TT];
    float c0 = 0.f, c1 = 0.f, s0 = 0.f, s1 = 0.f;
#pragma unroll
    for (int t = 0; t < TT; ++t) {
        float2 v = base[(size_t)t * (PLANE / 2) + tid];
        pix[t] = v;
        c0 += v.x; s0 += c0;
        c1 += v.y; s1 += c1;
    }

    // ---- Window argmax (first-max, reference candidate order a,a+1,a+W,a+W+1).
    // Partner pair (other row of the 2x2 window) is lane tid^32, same wave.
    const float os0 = __shfl_xor(s0, 32);
    const float os1 = __shfl_xor(s1, 32);
    const bool top = ((tid >> 5) & 1) == 0;   // rr even -> top row of window
    const float v0 = top ? s0  : os0;   // candidate a     (top-left)
    const float v1 = top ? s1  : os1;   // candidate a+1   (top-right)
    const float v2 = top ? os0 : s0;    // candidate a+W   (bottom-left)
    const float v3 = top ? os1 : s1;    // candidate a+W+1 (bottom-right)
    int win = 0; float bv = v0;
    if (v1 > bv) { bv = v1; win = 1; }
    if (v2 > bv) { bv = v2; win = 2; }
    if (v3 > bv) { bv = v3; win = 3; }
    // Both lanes of the pair compute the identical `win`.

    const int  col       = win & 1;                    // winner column within pair
    const bool needCross = top ? (win >= 2) : (win < 2); // winner on partner's row?

    // Output element for this pair: window (R*4 + wave, wo).
    // tid>>6 == wave id == window row within block (rr>>1). Same for tid^32.
    float* __restrict__ obase = out + (size_t)bc * OUT_BC_STRIDE
                              + (size_t)(R * 4 + (tid >> 6)) * WO + (tid & 31);

    // ---- Pass 2: winner gather straight from registers. Two timesteps per
    // iteration so both half-waves store (top lane writes t, bottom t+1). ----
#pragma unroll
    for (int t = 0; t < TT; t += 2) {
        const float m0 = col ? pix[t].y     : pix[t].x;
        const float m1 = col ? pix[t + 1].y : pix[t + 1].x;
        const float x0 = __shfl_xor(m0, 32);   // all lanes: shuffles pre-branch
        const float x1 = __shfl_xor(m1, 32);
        if (top) obase[(size_t)t       * OUT_T_STRIDE] = needCross ? x0 : m0;
        else     obase[(size_t)(t + 1) * OUT_T_STRIDE] = needCross ? x1 : m1;
    }

    // Scalar loss output (= 0.0f), appended after spk_rec.
    if (blk == 0 && tid == 0) out[N_OUT_MAIN] = 0.0f;
}

extern "C" void kernel_launch(void* const* d_in, const int* in_sizes, int n_in,
                              void* d_out, int out_size, void* d_ws, size_t ws_size,
                              hipStream_t stream) {
    const float* x = (const float*)d_in[0];
    float* out = (float*)d_out;
    dim3 grid(BB * CC * (HH / 8));   // 4096
    dim3 block(256);
    spike_pool_kernel<<<grid, block, 0, stream>>>(x, out);
}